// Round 7
// baseline (663.474 us; speedup 1.0000x reference)
//
#include <hip/hip_runtime.h>
#include <hip/hip_bf16.h>

#define D 512
#define L_LAYERS 2
#define BATCH 8
#define TT 2048
#define N3 1536   // 3*D
#define REC 4096  // BATCH*D
#define NFLAGS 32 // TT / 64 steps per flag unit

typedef __attribute__((ext_vector_type(8))) short short8;
typedef __attribute__((ext_vector_type(4))) float floatx4;

#if __has_builtin(__builtin_amdgcn_exp2f)
#define EXP2F(x) __builtin_amdgcn_exp2f(x)
#else
#define EXP2F(x) exp2f(x)
#endif
#if __has_builtin(__builtin_amdgcn_rcpf)
#define RCPF(x) __builtin_amdgcn_rcpf(x)
#else
#define RCPF(x) (1.0f / (x))
#endif

__device__ __forceinline__ unsigned short f2bf(float f) {
  unsigned u = __builtin_bit_cast(unsigned, f);
  u += 0x7FFFu + ((u >> 16) & 1u);
  return (unsigned short)(u >> 16);
}

// ---- embedding gather: xa[(t*B+b)*D + d] = bf16(emb[ids[b][t]][d])
__global__ __launch_bounds__(128) void embed_kernel(const int* __restrict__ ids,
                                                    const float* __restrict__ emb,
                                                    unsigned short* __restrict__ xa) {
  int bt = blockIdx.x;          // b*T + t
  int b = bt >> 11;
  int t = bt & 2047;
  int id = ids[bt];
  int d = threadIdx.x << 2;
  const float4 v = *(const float4*)(emb + (size_t)id * D + d);
  ushort4 w;
  w.x = f2bf(v.x); w.y = f2bf(v.y); w.z = f2bf(v.z); w.w = f2bf(v.w);
  *(ushort4*)(xa + ((size_t)t * BATCH + b) * D + d) = w;
}

// ---- W transpose + convert: Wt[l][n][k] = bf16(Ws[l][k][n]).
// Block 0, threads 248..255 also compute per-batch valid length (mask is
// monotone) -- fused here to save one kernel launch.
__global__ __launch_bounds__(256) void wconv_kernel(const float* __restrict__ Ws,
                                                    unsigned short* __restrict__ Wt,
                                                    const void* __restrict__ maskp,
                                                    int* __restrict__ lenb) {
  if (blockIdx.x == 0 && threadIdx.x >= 248) {
    int b = threadIdx.x - 248;
    int w0 = *(const int*)maskp;
    int mode = (w0 == 1) ? 0 : ((w0 == 0x01010101) ? 1 : 2);  // i32 / u8 / f32
    int lo = 0, hi = TT;
    while (lo < hi) {
      int mid = (lo + hi) >> 1;
      int idx = b * TT + mid;
      bool mm = (mode == 0) ? (((const int*)maskp)[idx] != 0)
              : (mode == 1) ? (((const unsigned char*)maskp)[idx] != 0)
                            : (((const float*)maskp)[idx] != 0.f);
      if (mm) lo = mid + 1; else hi = mid;
    }
    lenb[b] = lo;
  }
  int idx = blockIdx.x * 256 + threadIdx.x;
  if (idx >= L_LAYERS * D * N3) return;
  int n = idx % N3;
  int k = (idx / N3) % D;
  int l = idx / (N3 * D);
  Wt[((size_t)l * N3 + n) * D + k] = f2bf(Ws[idx]);
}

// ---- 3-plane NT bf16 MFMA GEMM, 2-phase double-buffered K-loop.
// One block computes a 128(m) x 128(dcol) output patch for ALL THREE planes
// (n = dcol, dcol+512, dcol+1024):
//   Ua[rec] u32 = u0 | u1<<16,  Uc[rec] u16 = u2   (rec = m*512+dcol, m=t*8+b)
// Block 0 also zeroes the chain-pipe flags (stream-ordered before the pipe
// kernel launches; re-zeroed each layer -> graph-replay safe).
__global__ __launch_bounds__(512) void gemm_kernel(const unsigned short* __restrict__ A,
                                                   const unsigned short* __restrict__ Bt,
                                                   unsigned* __restrict__ Ua32,
                                                   unsigned short* __restrict__ Uc16,
                                                   unsigned* __restrict__ flags) {
  constexpr int K = D;
  __shared__ __align__(16) unsigned short As[2][128 * 32];   // 16 KB
  __shared__ __align__(16) unsigned short Bs[2][384 * 32];   // 48 KB
  int tid = threadIdx.x;
  int lane = tid & 63;
  int wave = tid >> 6;           // 0..7
  int bi = blockIdx.x;
  if (bi == 0) {                 // zero 64*32 pipe flags
#pragma unroll
    for (int i = 0; i < 4; ++i) flags[tid * 4 + i] = 0u;
  }
  int xcd = bi & 7;
  int j = bi >> 3;               // 0..63
  int bm = xcd * 16 + (j >> 2);  // 0..127
  int dc0 = (j & 3) * 128;
  int m0 = bm * 128;
  int wm = (wave & 1) * 64;
  int w2 = wave >> 1;            // 0..3
  int q = lane >> 4, r16 = lane & 15;

  // staging geometry: each thread stages one 16B slot per plane per tile
  int arow = tid >> 2;           // 0..127
  int aoff = (tid & 3) * 8;      // ushort offset within 32-col row
  int nsrc[3];
#pragma unroll
  for (int i = 0; i < 3; ++i) {
    int c = arow + i * 128;      // Bs column 0..383
    int g = c >> 4;              // 0..23
    int p = g % 3;
    int dcol = (g / 3) * 16 + (c & 15);
    nsrc[i] = dc0 + dcol + p * 512;
  }
  const unsigned short* asrc = A + (size_t)(m0 + arow) * K + aoff;

  floatx4 acc[4][6] = {};

#define GSTAGE(bufi, k0s)                                                                  \
  {                                                                                        \
    __builtin_amdgcn_global_load_lds(                                                      \
        (const __attribute__((address_space(1))) unsigned int*)(asrc + (k0s)),             \
        (__attribute__((address_space(3))) unsigned int*)(&As[bufi][tid * 8]), 16, 0, 0);  \
    _Pragma("unroll")                                                                      \
    for (int i = 0; i < 3; ++i) {                                                          \
      __builtin_amdgcn_global_load_lds(                                                    \
          (const __attribute__((address_space(1))) unsigned int*)(Bt + (size_t)nsrc[i] * K + (k0s) + aoff), \
          (__attribute__((address_space(3))) unsigned int*)(&Bs[bufi][i * 4096 + tid * 8]), 16, 0, 0);      \
    }                                                                                      \
  }

  GSTAGE(0, 0);
  __syncthreads();               // buf0 ready
  int cur = 0;
  for (int k0 = 0; k0 < K; k0 += 32) {
    if (k0 + 32 < K) GSTAGE(cur ^ 1, k0 + 32);   // prefetch next tile
    short8 af[4], bfr[6];
#pragma unroll
    for (int i = 0; i < 4; ++i)
      af[i] = *(const short8*)&As[cur][(wm + i * 16 + r16) * 32 + q * 8];
#pragma unroll
    for (int i = 0; i < 6; ++i)
      bfr[i] = *(const short8*)&Bs[cur][(w2 * 96 + i * 16 + r16) * 32 + q * 8];
#pragma unroll
    for (int mi = 0; mi < 4; ++mi)
#pragma unroll
      for (int ni = 0; ni < 6; ++ni)
        acc[mi][ni] = __builtin_amdgcn_mfma_f32_16x16x32_bf16(af[mi], bfr[ni], acc[mi][ni], 0, 0, 0);
    __syncthreads();
    cur ^= 1;
  }
#undef GSTAGE

  // epilogue: C/D layout col=lane&15, row=(lane>>4)*4+reg (verified m89/m91)
#pragma unroll
  for (int mi = 0; mi < 4; ++mi)
#pragma unroll
    for (int half = 0; half < 2; ++half) {
      int dcol = dc0 + w2 * 32 + half * 16 + r16;
#pragma unroll
      for (int i = 0; i < 4; ++i) {
        int m = m0 + wm + mi * 16 + q * 4 + i;
        size_t rec = (size_t)m * D + dcol;
        unsigned ua = (unsigned)f2bf(acc[mi][half * 3 + 0][i]) |
                      ((unsigned)f2bf(acc[mi][half * 3 + 1][i]) << 16);
        Ua32[rec] = ua;
        Uc16[rec] = f2bf(acc[mi][half * 3 + 2][i]);
      }
    }
}

// ---- Fused pipeline: serial c-chain (producer CUs) || h epilogue (consumer
// CUs), one kernel, flag-gated. 256 blocks x 256 threads:
//   blocks 0..63   : the UNCHANGED proven cchain (1 wave, tid<64, no barriers).
//     Posts release-agent flag[p][f] after steps < (f+1)*64 are stored
//     (every 2nd chunk; ~400cyc vmcnt drain each, ~+5us total).
//   blocks 64..255 : hpost consumers. cc = bi-64; p = cc&63 (channel group =
//     producer p's 64 channels), s = cc>>6 (t-slice of ~683). Spin-wait
//     (acquire-agent + s_sleep, poll-capped) on flag, then compute h.
// R2/R5 lesson respected: producers' instruction stream untouched; h-work
// runs on DIFFERENT CUs. Cross-XCD visibility via agent-scope atomics (G16);
// consumer cc lands on producer p's XCD under round-robin (perf only).
// All 256 blocks co-resident even under worst-case packing -> no deadlock.
template <bool LAST>
__global__ __launch_bounds__(256) void chain_pipe_kernel(unsigned* __restrict__ Uac,
                                                         const unsigned short* __restrict__ Uc,
                                                         const unsigned short* __restrict__ Xin,
                                                         const float* __restrict__ vsl,
                                                         const float* __restrict__ bsl,
                                                         const int* __restrict__ lenb,
                                                         unsigned* __restrict__ flags,
                                                         unsigned short* __restrict__ Hout,
                                                         float* __restrict__ Out) {
  int bi = blockIdx.x;
  int tid = threadIdx.x;
  const float NL2E = -1.4426950408889634f;
  const float L2E2 = 2.8853900817779268f;

  if (bi < 64) {
    // ---------------- producer: serial c-chain ----------------
    if (tid >= 64) return;
    int ch = bi * 64 + tid;
    int b = ch >> 9;
    int d = ch & 511;
    int len = lenb[b];
    float vfe = NL2E * vsl[d];
    float cbf = NL2E * bsl[d];
    const unsigned* pa = Uac + ch;
    float* pc = (float*)Uac + ch;
    int nact = (len + 31) >> 5;   // 32..64 chunks of 32 steps
    unsigned* fbase = flags + bi * NFLAGS;

    unsigned uA[32], uB[32];

#define CLOAD(k, u)                                         \
  _Pragma("unroll") for (int j = 0; j < 32; ++j)            \
      u[j] = pa[(size_t)((k) * 32 + j) * REC];

#define CCOMP(k, u)                                         \
  _Pragma("unroll") for (int j = 0; j < 32; ++j) {          \
    unsigned a = u[j];                                      \
    float u0 = __builtin_bit_cast(float, a << 16);          \
    float u1f = __builtin_bit_cast(float, a & 0xFFFF0000u); \
    float k1 = fmaf(u1f, NL2E, cbf);                        \
    float a2 = fmaf(vfe, c, k1);                            \
    float e = EXP2F(a2);                                    \
    float inv = RCPF(e + 1.f);                              \
    c = fmaf(c - u0, inv, u0);                              \
    pc[(size_t)((k) * 32 + j) * REC] = c;                   \
  }

#define POST(f)                                                               \
  if (tid == 0) __hip_atomic_store(fbase + (f), 1u, __ATOMIC_RELEASE,         \
                                   __HIP_MEMORY_SCOPE_AGENT);

    CLOAD(0, uA);
    float c = 0.f;
    int k = 0;
    for (;;) {
      if (k + 1 < nact) CLOAD(k + 1, uB);
      CCOMP(k, uA);               // k even
      if (++k >= nact) break;
      if (k + 1 < nact) CLOAD(k + 1, uA);
      CCOMP(k, uB);               // k odd
      POST(k >> 1);               // covers steps < (k+1)*32
      if (++k >= nact) break;
    }
    // post remaining flags (covers last odd chunk + all-pad region)
    for (int f = nact >> 1; f < NFLAGS; ++f) POST(f);
#undef CLOAD
#undef CCOMP
#undef POST
  } else {
    // ---------------- consumer: h epilogue, flag-gated ----------------
    int cc = bi - 64;             // 0..191
    int p = cc & 63;              // producer / channel group
    int s = cc >> 6;              // t-slice 0..2
    int t_lo = s * 683;
    int t_hi = (s == 2) ? TT : (s + 1) * 683;
    int quad = tid & 15;
    int tr = tid >> 4;            // 0..15
    int rec0 = (p << 6) + (quad << 2);
    int bq = rec0 >> 9;
    int dq = rec0 & 511;
    int len = lenb[bq];
    const float4* cq = (const float4*)Uac;
    float4 vr4 = *(const float4*)(vsl + D + dq);
    float4 br4 = *(const float4*)(bsl + D + dq);
    float vra[4] = {vr4.x, vr4.y, vr4.z, vr4.w};
    float bra[4] = {br4.x, br4.y, br4.z, br4.w};
    unsigned* fp0 = flags + p * NFLAGS;

    int fl0 = t_lo >> 6, fl1 = (t_hi - 1) >> 6;
    for (int fl = fl0; fl <= fl1; ++fl) {
      // acquire-gate (poll-capped so bugs fail loudly instead of hanging)
      int guard = 1 << 18;
      while (__hip_atomic_load(fp0 + fl, __ATOMIC_ACQUIRE,
                               __HIP_MEMORY_SCOPE_AGENT) == 0 && --guard)
        __builtin_amdgcn_s_sleep(2);
      int ta = (t_lo > (fl << 6)) ? t_lo : (fl << 6);
      int tb = (t_hi < ((fl + 1) << 6)) ? t_hi : ((fl + 1) << 6);
      for (int t = ta + tr; t < tb; t += 16) {
        int idx = (t << 10) + (rec0 >> 2);
        ushort4 uv = *(const ushort4*)(Uc + (size_t)t * REC + rec0);
        ushort4 xv = *(const ushort4*)(Xin + (size_t)t * REC + rec0);
        float4 ct = cq[idx];
        float4 cp = (t > 0) ? cq[idx - 1024] : make_float4(0.f, 0.f, 0.f, 0.f);
        unsigned uu[4] = {uv.x, uv.y, uv.z, uv.w};
        unsigned xx[4] = {xv.x, xv.y, xv.z, xv.w};
        float cta[4] = {ct.x, ct.y, ct.z, ct.w};
        float cpa[4] = {cp.x, cp.y, cp.z, cp.w};
        bool act = t < len;
        float h[4];
#pragma unroll
        for (int jj = 0; jj < 4; ++jj) {
          float u2 = __builtin_bit_cast(float, uu[jj] << 16);
          float xf = __builtin_bit_cast(float, xx[jj] << 16);
          float k2 = fmaf(u2, NL2E, NL2E * bra[jj]);
          float a2 = fmaf(NL2E * vra[jj], cpa[jj], k2);
          float r = RCPF(EXP2F(a2) + 1.f);
          float et = EXP2F(cta[jj] * L2E2);
          float th = fmaf(-2.f, RCPF(et + 1.f), 1.f);
          float hv = fmaf(r, th - xf, xf);
          h[jj] = act ? hv : 0.f;   // cndmask kills NaN from stale c
        }
        if (LAST) {
          *(float4*)(Out + ((size_t)bq * TT + t) * D + dq) =
              make_float4(h[0], h[1], h[2], h[3]);
        } else {
          ushort4 o;
          o.x = f2bf(h[0]); o.y = f2bf(h[1]); o.z = f2bf(h[2]); o.w = f2bf(h[3]);
          *(ushort4*)(Hout + (size_t)t * REC + rec0) = o;
        }
      }
    }
  }
}

extern "C" void kernel_launch(void* const* d_in, const int* in_sizes, int n_in,
                              void* d_out, int out_size, void* d_ws, size_t ws_size,
                              hipStream_t stream) {
  const int* ids = (const int*)d_in[0];
  const void* mask = d_in[1];
  const float* emb = (const float*)d_in[2];
  const float* Ws = (const float*)d_in[3];
  const float* vs = (const float*)d_in[4];
  const float* bs = (const float*)d_in[5];
  float* out = (float*)d_out;

  char* ws = (char*)d_ws;
  unsigned short* Ua = (unsigned short*)ws;                   // 33.5 MB dword/rec (u0|u1; later c as f32)
  unsigned short* Uc = Ua + (size_t)TT * REC * 2;             // 16.8 MB ushort/rec (u2)
  unsigned short* xa = Uc + (size_t)TT * REC;                 // 16.8 MB
  unsigned short* xb = xa + (size_t)TT * REC;                 // 16.8 MB
  unsigned short* Wt = xb + (size_t)TT * REC;                 // 3.1 MB
  int* lenb = (int*)(Wt + (size_t)L_LAYERS * D * N3);
  unsigned* flags = (unsigned*)(lenb + 16);                   // 64*32 u32 = 8 KB

  embed_kernel<<<BATCH * TT, 128, 0, stream>>>(ids, emb, xa);
  wconv_kernel<<<(L_LAYERS * D * N3 + 255) / 256, 256, 0, stream>>>(Ws, Wt, mask, lenb);

  // layer 0
  gemm_kernel<<<512, 512, 0, stream>>>(xa, Wt, (unsigned*)Ua, Uc, flags);
  chain_pipe_kernel<false><<<256, 256, 0, stream>>>((unsigned*)Ua, Uc, xa,
                                                    vs, bs, lenb, flags, xb, nullptr);
  // layer 1
  gemm_kernel<<<512, 512, 0, stream>>>(xb, Wt + (size_t)N3 * D, (unsigned*)Ua, Uc, flags);
  chain_pipe_kernel<true><<<256, 256, 0, stream>>>((unsigned*)Ua, Uc, xb,
                                                   vs + 2 * D, bs + 2 * D, lenb, flags, nullptr, out);
}

// Round 8
// 568.992 us; speedup vs baseline: 1.1661x; 1.1661x over previous
//
#include <hip/hip_runtime.h>
#include <hip/hip_bf16.h>

#define D 512
#define L_LAYERS 2
#define BATCH 8
#define TT 2048
#define N3 1536   // 3*D
#define REC 4096  // BATCH*D

typedef __attribute__((ext_vector_type(8))) short short8;
typedef __attribute__((ext_vector_type(4))) float floatx4;

#if __has_builtin(__builtin_amdgcn_exp2f)
#define EXP2F(x) __builtin_amdgcn_exp2f(x)
#else
#define EXP2F(x) exp2f(x)
#endif
#if __has_builtin(__builtin_amdgcn_rcpf)
#define RCPF(x) __builtin_amdgcn_rcpf(x)
#else
#define RCPF(x) (1.0f / (x))
#endif

__device__ __forceinline__ unsigned short f2bf(float f) {
  unsigned u = __builtin_bit_cast(unsigned, f);
  u += 0x7FFFu + ((u >> 16) & 1u);
  return (unsigned short)(u >> 16);
}

// ---- embedding gather: xa[(t*B+b)*D + d] = bf16(emb[ids[b][t]][d])
__global__ __launch_bounds__(128) void embed_kernel(const int* __restrict__ ids,
                                                    const float* __restrict__ emb,
                                                    unsigned short* __restrict__ xa) {
  int bt = blockIdx.x;          // b*T + t
  int b = bt >> 11;
  int t = bt & 2047;
  int id = ids[bt];
  int d = threadIdx.x << 2;
  const float4 v = *(const float4*)(emb + (size_t)id * D + d);
  ushort4 w;
  w.x = f2bf(v.x); w.y = f2bf(v.y); w.z = f2bf(v.z); w.w = f2bf(v.w);
  *(ushort4*)(xa + ((size_t)t * BATCH + b) * D + d) = w;
}

// ---- W transpose + convert: Wt[l][n][k] = bf16(Ws[l][k][n]).
// Block 0, threads 248..255 also compute per-batch valid length (mask is
// monotone) -- fused here to save one kernel launch.
__global__ __launch_bounds__(256) void wconv_kernel(const float* __restrict__ Ws,
                                                    unsigned short* __restrict__ Wt,
                                                    const void* __restrict__ maskp,
                                                    int* __restrict__ lenb) {
  if (blockIdx.x == 0 && threadIdx.x >= 248) {
    int b = threadIdx.x - 248;
    int w0 = *(const int*)maskp;
    int mode = (w0 == 1) ? 0 : ((w0 == 0x01010101) ? 1 : 2);  // i32 / u8 / f32
    int lo = 0, hi = TT;
    while (lo < hi) {
      int mid = (lo + hi) >> 1;
      int idx = b * TT + mid;
      bool mm = (mode == 0) ? (((const int*)maskp)[idx] != 0)
              : (mode == 1) ? (((const unsigned char*)maskp)[idx] != 0)
                            : (((const float*)maskp)[idx] != 0.f);
      if (mm) lo = mid + 1; else hi = mid;
    }
    lenb[b] = lo;
  }
  int idx = blockIdx.x * 256 + threadIdx.x;
  if (idx >= L_LAYERS * D * N3) return;
  int n = idx % N3;
  int k = (idx / N3) % D;
  int l = idx / (N3 * D);
  Wt[((size_t)l * N3 + n) * D + k] = f2bf(Ws[idx]);
}

// ---- 3-plane NT bf16 MFMA GEMM, 2-phase double-buffered K-loop.
// One block computes a 128(m) x 128(dcol) output patch for ALL THREE planes
// (n = dcol, dcol+512, dcol+1024):
//   Ua[rec] u32 = u0 | u1<<16,  Uc[rec] u16 = u2   (rec = m*512+dcol, m=t*8+b)
// K-loop: issue STAGE(next) BEFORE computing current buffer; one barrier per
// iteration. LDS 64KB -> 2 blocks/CU. Bs columns interleaved per-16 (plane
// p = (c>>4)%3). 512 threads / 8 waves: wave covers 64m x 96c -> acc[4][6].
// XCD swizzle: 4 dcol-blocks of same bm share the A-panel in L2.
__global__ __launch_bounds__(512) void gemm_kernel(const unsigned short* __restrict__ A,
                                                   const unsigned short* __restrict__ Bt,
                                                   unsigned* __restrict__ Ua32,
                                                   unsigned short* __restrict__ Uc16) {
  constexpr int K = D;
  __shared__ __align__(16) unsigned short As[2][128 * 32];   // 16 KB
  __shared__ __align__(16) unsigned short Bs[2][384 * 32];   // 48 KB
  int tid = threadIdx.x;
  int lane = tid & 63;
  int wave = tid >> 6;           // 0..7
  int bi = blockIdx.x;
  int xcd = bi & 7;
  int j = bi >> 3;               // 0..63
  int bm = xcd * 16 + (j >> 2);  // 0..127
  int dc0 = (j & 3) * 128;
  int m0 = bm * 128;
  int wm = (wave & 1) * 64;
  int w2 = wave >> 1;            // 0..3
  int q = lane >> 4, r16 = lane & 15;

  // staging geometry: each thread stages one 16B slot per plane per tile
  int arow = tid >> 2;           // 0..127
  int aoff = (tid & 3) * 8;      // ushort offset within 32-col row
  int nsrc[3];
#pragma unroll
  for (int i = 0; i < 3; ++i) {
    int c = arow + i * 128;      // Bs column 0..383
    int g = c >> 4;              // 0..23
    int p = g % 3;
    int dcol = (g / 3) * 16 + (c & 15);
    nsrc[i] = dc0 + dcol + p * 512;
  }
  const unsigned short* asrc = A + (size_t)(m0 + arow) * K + aoff;

  floatx4 acc[4][6] = {};

#define GSTAGE(bufi, k0s)                                                                  \
  {                                                                                        \
    __builtin_amdgcn_global_load_lds(                                                      \
        (const __attribute__((address_space(1))) unsigned int*)(asrc + (k0s)),             \
        (__attribute__((address_space(3))) unsigned int*)(&As[bufi][tid * 8]), 16, 0, 0);  \
    _Pragma("unroll")                                                                      \
    for (int i = 0; i < 3; ++i) {                                                          \
      __builtin_amdgcn_global_load_lds(                                                    \
          (const __attribute__((address_space(1))) unsigned int*)(Bt + (size_t)nsrc[i] * K + (k0s) + aoff), \
          (__attribute__((address_space(3))) unsigned int*)(&Bs[bufi][i * 4096 + tid * 8]), 16, 0, 0);      \
    }                                                                                      \
  }

  GSTAGE(0, 0);
  __syncthreads();               // buf0 ready
  int cur = 0;
  for (int k0 = 0; k0 < K; k0 += 32) {
    if (k0 + 32 < K) GSTAGE(cur ^ 1, k0 + 32);   // prefetch next tile
    short8 af[4], bfr[6];
#pragma unroll
    for (int i = 0; i < 4; ++i)
      af[i] = *(const short8*)&As[cur][(wm + i * 16 + r16) * 32 + q * 8];
#pragma unroll
    for (int i = 0; i < 6; ++i)
      bfr[i] = *(const short8*)&Bs[cur][(w2 * 96 + i * 16 + r16) * 32 + q * 8];
#pragma unroll
    for (int mi = 0; mi < 4; ++mi)
#pragma unroll
      for (int ni = 0; ni < 6; ++ni)
        acc[mi][ni] = __builtin_amdgcn_mfma_f32_16x16x32_bf16(af[mi], bfr[ni], acc[mi][ni], 0, 0, 0);
    __syncthreads();
    cur ^= 1;
  }
#undef GSTAGE

  // epilogue: C/D layout col=lane&15, row=(lane>>4)*4+reg (verified m89/m91)
#pragma unroll
  for (int mi = 0; mi < 4; ++mi)
#pragma unroll
    for (int half = 0; half < 2; ++half) {
      int dcol = dc0 + w2 * 32 + half * 16 + r16;
#pragma unroll
      for (int i = 0; i < 4; ++i) {
        int m = m0 + wm + mi * 16 + q * 4 + i;
        size_t rec = (size_t)m * D + dcol;
        unsigned ua = (unsigned)f2bf(acc[mi][half * 3 + 0][i]) |
                      ((unsigned)f2bf(acc[mi][half * 3 + 1][i]) << 16);
        Ua32[rec] = ua;
        Uc16[rec] = f2bf(acc[mi][half * 3 + 2][i]);
      }
    }
}

// ---- Kernel A: serial c-chain, 2 chains per lane (cross-chain ILP).
// 32 blocks x 64 threads; lane owns channels ch0 = blk*128+lane and
// ch1 = ch0+64 (same batch b). The two recurrences are independent, so
// their instruction streams interleave in the in-order wave: while chain0
// waits on exp/rcp latency (~100 cyc of the ~109 cyc/step), chain1 issues.
// Expected ~55-65 cyc per chain-step. R2/R5/R7 lesson: NO foreign work in
// this kernel -- only more of the same recurrence, which adds zero trans
// ops to either critical path. Chunk=16, register double-buffered
// (4 x 16 u32 staging = 64 VGPR; in-flight vmem <= 64).
__global__ __launch_bounds__(64) void cchain_kernel(unsigned* __restrict__ Uac,
                                                    const float* __restrict__ vsl,
                                                    const float* __restrict__ bsl,
                                                    const int* __restrict__ lenb) {
  int tid = threadIdx.x;
  int ch0 = blockIdx.x * 128 + tid;   // chain 0
  int ch1 = ch0 + 64;                 // chain 1
  int b = ch0 >> 9;                   // uniform per block (128 | 512)
  int d0 = ch0 & 511, d1 = ch1 & 511;
  int len = lenb[b];
  const float NL2E = -1.4426950408889634f;
  float vfe0 = NL2E * vsl[d0], cbf0 = NL2E * bsl[d0];
  float vfe1 = NL2E * vsl[d1], cbf1 = NL2E * bsl[d1];
  const unsigned* pa0 = Uac + ch0;
  const unsigned* pa1 = Uac + ch1;
  float* pc0 = (float*)Uac + ch0;
  float* pc1 = (float*)Uac + ch1;
  int nact = (len + 15) >> 4;         // 64..128 chunks of 16 steps

  unsigned uA0[16], uA1[16], uB0[16], uB1[16];

#define CLOAD2(k, u0a, u1a)                                 \
  _Pragma("unroll") for (int j = 0; j < 16; ++j) {          \
    u0a[j] = pa0[(size_t)((k) * 16 + j) * REC];             \
    u1a[j] = pa1[(size_t)((k) * 16 + j) * REC];             \
  }

#define CCOMP2(k, u0a, u1a)                                 \
  _Pragma("unroll") for (int j = 0; j < 16; ++j) {          \
    unsigned a0 = u0a[j], a1 = u1a[j];                      \
    float u00 = __builtin_bit_cast(float, a0 << 16);        \
    float u01 = __builtin_bit_cast(float, a1 << 16);        \
    float u10 = __builtin_bit_cast(float, a0 & 0xFFFF0000u);\
    float u11 = __builtin_bit_cast(float, a1 & 0xFFFF0000u);\
    float k10 = fmaf(u10, NL2E, cbf0);                      \
    float k11 = fmaf(u11, NL2E, cbf1);                      \
    float a20 = fmaf(vfe0, c0, k10);                        \
    float a21 = fmaf(vfe1, c1, k11);                        \
    float e0 = EXP2F(a20);                                  \
    float e1 = EXP2F(a21);                                  \
    float i0 = RCPF(e0 + 1.f);                              \
    float i1 = RCPF(e1 + 1.f);                              \
    c0 = fmaf(c0 - u00, i0, u00);                           \
    c1 = fmaf(c1 - u01, i1, u01);                           \
    pc0[(size_t)((k) * 16 + j) * REC] = c0;                 \
    pc1[(size_t)((k) * 16 + j) * REC] = c1;                 \
  }

  CLOAD2(0, uA0, uA1);
  float c0 = 0.f, c1 = 0.f;
  int k = 0;
  for (;;) {
    if (k + 1 < nact) CLOAD2(k + 1, uB0, uB1);
    CCOMP2(k, uA0, uA1);
    if (++k >= nact) break;
    if (k + 1 < nact) CLOAD2(k + 1, uA0, uA1);
    CCOMP2(k, uB0, uB1);
    if (++k >= nact) break;
  }
#undef CLOAD2
#undef CCOMP2
  // t >= nact*16: c region stale; hpost masks h=0 there, never reads stale c into output.
}

// ---- Kernel B: parallel h epilogue. h_t = r*tanh(c_t) + (1-r)*x, r = sigm(u2+vr*c_{t-1}+br).
// u2 from Uc (ushort plane), x from the layer input xa/xb (same rec layout).
template <bool LAST>
__global__ __launch_bounds__(256) void hpost_kernel(const unsigned short* __restrict__ Uc,
                                                    const unsigned short* __restrict__ Xin,
                                                    const float4* __restrict__ cq,
                                                    const float* __restrict__ vsl,
                                                    const float* __restrict__ bsl,
                                                    const int* __restrict__ lenb,
                                                    unsigned short* __restrict__ Hout,
                                                    float* __restrict__ Out) {
  int idx = blockIdx.x * 256 + threadIdx.x;   // = t*1024 + q
  int t = idx >> 10;
  int q = idx & 1023;
  int rec0 = q << 2;
  int b = rec0 >> 9;
  int d = rec0 & 511;
  int len = lenb[b];
  ushort4 uv = *(const ushort4*)(Uc + (size_t)idx * 4);
  ushort4 xv = *(const ushort4*)(Xin + (size_t)idx * 4);
  float4 ct = cq[idx];
  float4 cp = (t > 0) ? cq[idx - 1024] : make_float4(0.f, 0.f, 0.f, 0.f);
  float4 vr4 = *(const float4*)(vsl + D + d);
  float4 br4 = *(const float4*)(bsl + D + d);
  const float NL2E = -1.4426950408889634f;
  const float L2E2 = 2.8853900817779268f;
  unsigned uu[4] = {uv.x, uv.y, uv.z, uv.w};
  unsigned xx[4] = {xv.x, xv.y, xv.z, xv.w};
  float cta[4] = {ct.x, ct.y, ct.z, ct.w};
  float cpa[4] = {cp.x, cp.y, cp.z, cp.w};
  float vra[4] = {vr4.x, vr4.y, vr4.z, vr4.w};
  float bra[4] = {br4.x, br4.y, br4.z, br4.w};
  bool act = t < len;
  float h[4];
#pragma unroll
  for (int j = 0; j < 4; ++j) {
    float u2 = __builtin_bit_cast(float, uu[j] << 16);
    float xf = __builtin_bit_cast(float, xx[j] << 16);
    float k2 = fmaf(u2, NL2E, NL2E * bra[j]);
    float a2 = fmaf(NL2E * vra[j], cpa[j], k2);
    float r = RCPF(EXP2F(a2) + 1.f);
    float et = EXP2F(cta[j] * L2E2);
    float th = fmaf(-2.f, RCPF(et + 1.f), 1.f);
    float hv = fmaf(r, th - xf, xf);
    h[j] = act ? hv : 0.f;
  }
  if (LAST) {
    *(float4*)(Out + ((size_t)b * TT + t) * D + d) = make_float4(h[0], h[1], h[2], h[3]);
  } else {
    ushort4 o; o.x = f2bf(h[0]); o.y = f2bf(h[1]); o.z = f2bf(h[2]); o.w = f2bf(h[3]);
    *(ushort4*)(Hout + (size_t)idx * 4) = o;    // (t*8+b)*512+d == idx*4
  }
}

extern "C" void kernel_launch(void* const* d_in, const int* in_sizes, int n_in,
                              void* d_out, int out_size, void* d_ws, size_t ws_size,
                              hipStream_t stream) {
  const int* ids = (const int*)d_in[0];
  const void* mask = d_in[1];
  const float* emb = (const float*)d_in[2];
  const float* Ws = (const float*)d_in[3];
  const float* vs = (const float*)d_in[4];
  const float* bs = (const float*)d_in[5];
  float* out = (float*)d_out;

  char* ws = (char*)d_ws;
  unsigned short* Ua = (unsigned short*)ws;                   // 33.5 MB dword/rec (u0|u1; later c as f32)
  unsigned short* Uc = Ua + (size_t)TT * REC * 2;             // 16.8 MB ushort/rec (u2)
  unsigned short* xa = Uc + (size_t)TT * REC;                 // 16.8 MB
  unsigned short* xb = xa + (size_t)TT * REC;                 // 16.8 MB
  unsigned short* Wt = xb + (size_t)TT * REC;                 // 3.1 MB
  int* lenb = (int*)(Wt + (size_t)L_LAYERS * D * N3);

  embed_kernel<<<BATCH * TT, 128, 0, stream>>>(ids, emb, xa);
  wconv_kernel<<<(L_LAYERS * D * N3 + 255) / 256, 256, 0, stream>>>(Ws, Wt, mask, lenb);

  // layer 0
  gemm_kernel<<<512, 512, 0, stream>>>(xa, Wt, (unsigned*)Ua, Uc);
  cchain_kernel<<<32, 64, 0, stream>>>((unsigned*)Ua, vs, bs, lenb);
  hpost_kernel<false><<<8192, 256, 0, stream>>>(Uc, xa, (const float4*)Ua,
                                                vs, bs, lenb, xb, nullptr);
  // layer 1
  gemm_kernel<<<512, 512, 0, stream>>>(xb, Wt + (size_t)N3 * D, (unsigned*)Ua, Uc);
  cchain_kernel<<<32, 64, 0, stream>>>((unsigned*)Ua, vs + 2 * D, bs + 2 * D, lenb);
  hpost_kernel<true><<<8192, 256, 0, stream>>>(Uc, xb, (const float4*)Ua,
                                               vs + 2 * D, bs + 2 * D, lenb, nullptr, out);
}

// Round 9
// 405.607 us; speedup vs baseline: 1.6358x; 1.4028x over previous
//
#include <hip/hip_runtime.h>
#include <hip/hip_bf16.h>

#define D 512
#define L_LAYERS 2
#define BATCH 8
#define TT 2048
#define N3 1536   // 3*D
#define REC 4096  // BATCH*D
#define HALF_IDX (1024 * 1024)   // idx of t=1024 in (t*1024+q) space

typedef __attribute__((ext_vector_type(8))) short short8;
typedef __attribute__((ext_vector_type(4))) float floatx4;

#if __has_builtin(__builtin_amdgcn_exp2f)
#define EXP2F(x) __builtin_amdgcn_exp2f(x)
#else
#define EXP2F(x) exp2f(x)
#endif
#if __has_builtin(__builtin_amdgcn_rcpf)
#define RCPF(x) __builtin_amdgcn_rcpf(x)
#else
#define RCPF(x) (1.0f / (x))
#endif

__device__ __forceinline__ unsigned short f2bf(float f) {
  unsigned u = __builtin_bit_cast(unsigned, f);
  u += 0x7FFFu + ((u >> 16) & 1u);
  return (unsigned short)(u >> 16);
}

// ---- embedding gather: xa[(t*B+b)*D + d] = bf16(emb[ids[b][t]][d])
__global__ __launch_bounds__(128) void embed_kernel(const int* __restrict__ ids,
                                                    const float* __restrict__ emb,
                                                    unsigned short* __restrict__ xa) {
  int bt = blockIdx.x;          // b*T + t
  int b = bt >> 11;
  int t = bt & 2047;
  int id = ids[bt];
  int d = threadIdx.x << 2;
  const float4 v = *(const float4*)(emb + (size_t)id * D + d);
  ushort4 w;
  w.x = f2bf(v.x); w.y = f2bf(v.y); w.z = f2bf(v.z); w.w = f2bf(v.w);
  *(ushort4*)(xa + ((size_t)t * BATCH + b) * D + d) = w;
}

// ---- W transpose + convert: Wt[l][n][k] = bf16(Ws[l][k][n]).
// Block 0, threads 248..255 also compute per-batch valid length.
__global__ __launch_bounds__(256) void wconv_kernel(const float* __restrict__ Ws,
                                                    unsigned short* __restrict__ Wt,
                                                    const void* __restrict__ maskp,
                                                    int* __restrict__ lenb) {
  if (blockIdx.x == 0 && threadIdx.x >= 248) {
    int b = threadIdx.x - 248;
    int w0 = *(const int*)maskp;
    int mode = (w0 == 1) ? 0 : ((w0 == 0x01010101) ? 1 : 2);  // i32 / u8 / f32
    int lo = 0, hi = TT;
    while (lo < hi) {
      int mid = (lo + hi) >> 1;
      int idx = b * TT + mid;
      bool mm = (mode == 0) ? (((const int*)maskp)[idx] != 0)
              : (mode == 1) ? (((const unsigned char*)maskp)[idx] != 0)
                            : (((const float*)maskp)[idx] != 0.f);
      if (mm) lo = mid + 1; else hi = mid;
    }
    lenb[b] = lo;
  }
  int idx = blockIdx.x * 256 + threadIdx.x;
  if (idx >= L_LAYERS * D * N3) return;
  int n = idx % N3;
  int k = (idx / N3) % D;
  int l = idx / (N3 * D);
  Wt[((size_t)l * N3 + n) * D + k] = f2bf(Ws[idx]);
}

// ==== GEMM body (proven R6 2-phase double-buffered 3-plane), bm-ranged.
// bi in [0,256): xcd=bi&7, j=bi>>3 (0..31), bm=bm_base+xcd*8+(j>>2),
// dc0=(j&3)*128. Computes Ua[rec]=u0|u1<<16, Uc[rec]=u2 for its patch.
__device__ __forceinline__ void gemm_body(int bi, int bm_base,
                                          const unsigned short* __restrict__ A,
                                          const unsigned short* __restrict__ Bt,
                                          unsigned* __restrict__ Ua32,
                                          unsigned short* __restrict__ Uc16,
                                          unsigned short* As,    // 2*4096
                                          unsigned short* Bs) {  // 2*12288
  constexpr int K = D;
  int tid = threadIdx.x;
  int lane = tid & 63;
  int wave = tid >> 6;           // 0..7
  int xcd = bi & 7;
  int j = bi >> 3;               // 0..31
  int bm = bm_base + xcd * 8 + (j >> 2);
  int dc0 = (j & 3) * 128;
  int m0 = bm * 128;
  int wm = (wave & 1) * 64;
  int w2 = wave >> 1;            // 0..3
  int q = lane >> 4, r16 = lane & 15;

  int arow = tid >> 2;           // 0..127
  int aoff = (tid & 3) * 8;
  int nsrc[3];
#pragma unroll
  for (int i = 0; i < 3; ++i) {
    int c = arow + i * 128;
    int g = c >> 4;
    int p = g % 3;
    int dcol = (g / 3) * 16 + (c & 15);
    nsrc[i] = dc0 + dcol + p * 512;
  }
  const unsigned short* asrc = A + (size_t)(m0 + arow) * K + aoff;

  floatx4 acc[4][6] = {};

#define GSTAGE(bufi, k0s)                                                                  \
  {                                                                                        \
    __builtin_amdgcn_global_load_lds(                                                      \
        (const __attribute__((address_space(1))) unsigned int*)(asrc + (k0s)),             \
        (__attribute__((address_space(3))) unsigned int*)(As + (bufi) * 4096 + tid * 8), 16, 0, 0); \
    _Pragma("unroll")                                                                      \
    for (int i = 0; i < 3; ++i) {                                                          \
      __builtin_amdgcn_global_load_lds(                                                    \
          (const __attribute__((address_space(1))) unsigned int*)(Bt + (size_t)nsrc[i] * K + (k0s) + aoff), \
          (__attribute__((address_space(3))) unsigned int*)(Bs + (bufi) * 12288 + i * 4096 + tid * 8), 16, 0, 0); \
    }                                                                                      \
  }

  GSTAGE(0, 0);
  __syncthreads();
  int cur = 0;
  for (int k0 = 0; k0 < K; k0 += 32) {
    if (k0 + 32 < K) GSTAGE(cur ^ 1, k0 + 32);
    short8 af[4], bfr[6];
#pragma unroll
    for (int i = 0; i < 4; ++i)
      af[i] = *(const short8*)&As[cur * 4096 + (wm + i * 16 + r16) * 32 + q * 8];
#pragma unroll
    for (int i = 0; i < 6; ++i)
      bfr[i] = *(const short8*)&Bs[cur * 12288 + (w2 * 96 + i * 16 + r16) * 32 + q * 8];
#pragma unroll
    for (int mi = 0; mi < 4; ++mi)
#pragma unroll
      for (int ni = 0; ni < 6; ++ni)
        acc[mi][ni] = __builtin_amdgcn_mfma_f32_16x16x32_bf16(af[mi], bfr[ni], acc[mi][ni], 0, 0, 0);
    __syncthreads();
    cur ^= 1;
  }
#undef GSTAGE

  // epilogue: C/D layout col=lane&15, row=(lane>>4)*4+reg
#pragma unroll
  for (int mi = 0; mi < 4; ++mi)
#pragma unroll
    for (int half = 0; half < 2; ++half) {
      int dcol = dc0 + w2 * 32 + half * 16 + r16;
#pragma unroll
      for (int i = 0; i < 4; ++i) {
        int m = m0 + wm + mi * 16 + q * 4 + i;
        size_t rec = (size_t)m * D + dcol;
        unsigned ua = (unsigned)f2bf(acc[mi][half * 3 + 0][i]) |
                      ((unsigned)f2bf(acc[mi][half * 3 + 1][i]) << 16);
        Ua32[rec] = ua;
        Uc16[rec] = f2bf(acc[mi][half * 3 + 2][i]);
      }
    }
}

// ==== chain body (proven R6 single-chain), t-ranged [t0,t1).
// len >= 1024 so [0,1024) is always fully active. Writes c (f32) over Ua.
// Carries c across the t=1024 boundary via csave.
__device__ __forceinline__ void chain_body(unsigned* __restrict__ Uac,
                                           const float* __restrict__ vsl,
                                           const float* __restrict__ bsl,
                                           const int* __restrict__ lenb,
                                           float* __restrict__ csave,
                                           int ch, int t0, int t1) {
  int b = ch >> 9;
  int d = ch & 511;
  int len = lenb[b];
  const float NL2E = -1.4426950408889634f;
  float vfe = NL2E * vsl[d];
  float cbf = NL2E * bsl[d];
  const unsigned* pa = Uac + ch;
  float* pc = (float*)Uac + ch;
  int nact = (len + 31) >> 5;
  int kbeg = t0 >> 5;
  int kend = t1 >> 5;
  if (nact < kend) kend = nact;     // chain1 may stop early; chain0: kend=32<=nact

  unsigned uA[32], uB[32];

#define CLOAD(k, u)                                         \
  _Pragma("unroll") for (int j = 0; j < 32; ++j)            \
      u[j] = pa[(size_t)((k) * 32 + j) * REC];

#define CCOMP(k, u)                                         \
  _Pragma("unroll") for (int j = 0; j < 32; ++j) {          \
    unsigned a = u[j];                                      \
    float u0 = __builtin_bit_cast(float, a << 16);          \
    float u1f = __builtin_bit_cast(float, a & 0xFFFF0000u); \
    float k1 = fmaf(u1f, NL2E, cbf);                        \
    float a2 = fmaf(vfe, c, k1);                            \
    float e = EXP2F(a2);                                    \
    float inv = RCPF(e + 1.f);                              \
    c = fmaf(c - u0, inv, u0);                              \
    pc[(size_t)((k) * 32 + j) * REC] = c;                   \
  }

  float c = (t0 == 0) ? 0.f : csave[ch];
  if (kbeg < kend) {
    CLOAD(kbeg, uA);
    int k = kbeg;
    for (;;) {
      if (k + 1 < kend) CLOAD(k + 1, uB);
      CCOMP(k, uA);
      if (++k >= kend) break;
      if (k + 1 < kend) CLOAD(k + 1, uA);
      CCOMP(k, uB);
      if (++k >= kend) break;
    }
  }
#undef CLOAD
#undef CCOMP
  if (t1 < TT) csave[ch] = c;       // hand off to the t>=1024 half
  // t >= nact*32: c stale; hpost masks h=0 there.
}

// ==== hpost body (proven R6), idx-parameterized. idx = t*1024 + q.
template <bool LAST>
__device__ __forceinline__ void hpost_body(int idx,
                                           const unsigned short* __restrict__ Uc,
                                           const unsigned short* __restrict__ Xin,
                                           const float4* __restrict__ cq,
                                           const float* __restrict__ vsl,
                                           const float* __restrict__ bsl,
                                           const int* __restrict__ lenb,
                                           unsigned short* __restrict__ Hout,
                                           float* __restrict__ Out) {
  int t = idx >> 10;
  int q = idx & 1023;
  int rec0 = q << 2;
  int b = rec0 >> 9;
  int d = rec0 & 511;
  int len = lenb[b];
  ushort4 uv = *(const ushort4*)(Uc + (size_t)idx * 4);
  ushort4 xv = *(const ushort4*)(Xin + (size_t)idx * 4);
  float4 ct = cq[idx];
  float4 cp = (t > 0) ? cq[idx - 1024] : make_float4(0.f, 0.f, 0.f, 0.f);
  float4 vr4 = *(const float4*)(vsl + D + d);
  float4 br4 = *(const float4*)(bsl + D + d);
  const float NL2E = -1.4426950408889634f;
  const float L2E2 = 2.8853900817779268f;
  unsigned uu[4] = {uv.x, uv.y, uv.z, uv.w};
  unsigned xx[4] = {xv.x, xv.y, xv.z, xv.w};
  float cta[4] = {ct.x, ct.y, ct.z, ct.w};
  float cpa[4] = {cp.x, cp.y, cp.z, cp.w};
  float vra[4] = {vr4.x, vr4.y, vr4.z, vr4.w};
  float bra[4] = {br4.x, br4.y, br4.z, br4.w};
  bool act = t < len;
  float h[4];
#pragma unroll
  for (int j = 0; j < 4; ++j) {
    float u2 = __builtin_bit_cast(float, uu[j] << 16);
    float xf = __builtin_bit_cast(float, xx[j] << 16);
    float k2 = fmaf(u2, NL2E, NL2E * bra[j]);
    float a2 = fmaf(NL2E * vra[j], cpa[j], k2);
    float r = RCPF(EXP2F(a2) + 1.f);
    float et = EXP2F(cta[j] * L2E2);
    float th = fmaf(-2.f, RCPF(et + 1.f), 1.f);
    float hv = fmaf(r, th - xf, xf);
    h[j] = act ? hv : 0.f;
  }
  if (LAST) {
    *(float4*)(Out + ((size_t)b * TT + t) * D + d) = make_float4(h[0], h[1], h[2], h[3]);
  } else {
    ushort4 o; o.x = f2bf(h[0]); o.y = f2bf(h[1]); o.z = f2bf(h[2]); o.w = f2bf(h[3]);
    *(ushort4*)(Hout + (size_t)idx * 4) = o;
  }
}

// ==== K1: pure GEMM, bm 0..63 (t < 1024)
__global__ __launch_bounds__(512) void gemm_kernel(const unsigned short* __restrict__ A,
                                                   const unsigned short* __restrict__ Bt,
                                                   unsigned* __restrict__ Ua32,
                                                   unsigned short* __restrict__ Uc16,
                                                   int bm_base) {
  __shared__ __align__(16) unsigned short As[2 * 4096];
  __shared__ __align__(16) unsigned short Bs[2 * 12288];
  gemm_body(blockIdx.x, bm_base, A, Bt, Ua32, Uc16, As, Bs);
}

// ==== K2: chain t<1024 (blocks 0..63, started first) || GEMM bm 64..127.
// Disjoint Ua rows (chain r/w t<1024; gemm writes t>=1024). No fences needed:
// all producer->consumer deps cross kernel boundaries.
__global__ __launch_bounds__(512) void gc_kernel(const unsigned short* __restrict__ A,
                                                 const unsigned short* __restrict__ Bt,
                                                 unsigned* __restrict__ Ua32,
                                                 unsigned short* __restrict__ Uc16,
                                                 const float* __restrict__ vsl,
                                                 const float* __restrict__ bsl,
                                                 const int* __restrict__ lenb,
                                                 float* __restrict__ csave) {
  __shared__ __align__(16) unsigned short As[2 * 4096];
  __shared__ __align__(16) unsigned short Bs[2 * 12288];
  int bi = blockIdx.x;
  if (bi < 64) {
    if (threadIdx.x >= 64) return;
    chain_body(Ua32, vsl, bsl, lenb, csave, bi * 64 + threadIdx.x, 0, 1024);
  } else {
    gemm_body(bi - 64, 64, A, Bt, Ua32, Uc16, As, Bs);
  }
}

// ==== K3: chain t>=1024 (blocks 0..63) || hpost t<1024 (blocks 64..4159).
// Disjoint Ua rows (chain writes c t>=1024; hpost reads c t<1024).
template <bool LAST>
__global__ __launch_bounds__(256) void ch_kernel(unsigned* __restrict__ Uac,
                                                 const unsigned short* __restrict__ Uc,
                                                 const unsigned short* __restrict__ Xin,
                                                 const float* __restrict__ vsl,
                                                 const float* __restrict__ bsl,
                                                 const int* __restrict__ lenb,
                                                 float* __restrict__ csave,
                                                 unsigned short* __restrict__ Hout,
                                                 float* __restrict__ Out) {
  int bi = blockIdx.x;
  if (bi < 64) {
    if (threadIdx.x >= 64) return;
    chain_body(Uac, vsl, bsl, lenb, csave, bi * 64 + threadIdx.x, 1024, 2048);
  } else {
    hpost_body<LAST>((bi - 64) * 256 + threadIdx.x, Uc, Xin, (const float4*)Uac,
                     vsl, bsl, lenb, Hout, Out);
  }
}

// ==== K4: pure hpost, t >= 1024
template <bool LAST>
__global__ __launch_bounds__(256) void hpost_kernel(const unsigned short* __restrict__ Uc,
                                                    const unsigned short* __restrict__ Xin,
                                                    const float4* __restrict__ cq,
                                                    const float* __restrict__ vsl,
                                                    const float* __restrict__ bsl,
                                                    const int* __restrict__ lenb,
                                                    unsigned short* __restrict__ Hout,
                                                    float* __restrict__ Out) {
  hpost_body<LAST>(HALF_IDX + blockIdx.x * 256 + threadIdx.x, Uc, Xin, cq,
                   vsl, bsl, lenb, Hout, Out);
}

extern "C" void kernel_launch(void* const* d_in, const int* in_sizes, int n_in,
                              void* d_out, int out_size, void* d_ws, size_t ws_size,
                              hipStream_t stream) {
  const int* ids = (const int*)d_in[0];
  const void* mask = d_in[1];
  const float* emb = (const float*)d_in[2];
  const float* Ws = (const float*)d_in[3];
  const float* vs = (const float*)d_in[4];
  const float* bs = (const float*)d_in[5];
  float* out = (float*)d_out;

  char* ws = (char*)d_ws;
  unsigned short* Ua = (unsigned short*)ws;                   // 33.5 MB dword/rec (u0|u1; later c as f32)
  unsigned short* Uc = Ua + (size_t)TT * REC * 2;             // 16.8 MB ushort/rec (u2)
  unsigned short* xa = Uc + (size_t)TT * REC;                 // 16.8 MB
  unsigned short* xb = xa + (size_t)TT * REC;                 // 16.8 MB
  unsigned short* Wt = xb + (size_t)TT * REC;                 // 3.1 MB
  int* lenb = (int*)(Wt + (size_t)L_LAYERS * D * N3);
  float* csave = (float*)(lenb + 16);                         // 4096 f32 = 16 KB

  embed_kernel<<<BATCH * TT, 128, 0, stream>>>(ids, emb, xa);
  wconv_kernel<<<(L_LAYERS * D * N3 + 255) / 256, 256, 0, stream>>>(Ws, Wt, mask, lenb);

  // layer 0 (4-stage software pipeline over t-halves)
  gemm_kernel<<<256, 512, 0, stream>>>(xa, Wt, (unsigned*)Ua, Uc, 0);
  gc_kernel<<<320, 512, 0, stream>>>(xa, Wt, (unsigned*)Ua, Uc, vs, bs, lenb, csave);
  ch_kernel<false><<<4160, 256, 0, stream>>>((unsigned*)Ua, Uc, xa, vs, bs, lenb,
                                             csave, xb, nullptr);
  hpost_kernel<false><<<4096, 256, 0, stream>>>(Uc, xa, (const float4*)Ua,
                                                vs, bs, lenb, xb, nullptr);
  // layer 1
  gemm_kernel<<<256, 512, 0, stream>>>(xb, Wt + (size_t)N3 * D, (unsigned*)Ua, Uc, 0);
  gc_kernel<<<320, 512, 0, stream>>>(xb, Wt + (size_t)N3 * D, (unsigned*)Ua, Uc,
                                     vs + 2 * D, bs + 2 * D, lenb, csave);
  ch_kernel<true><<<4160, 256, 0, stream>>>((unsigned*)Ua, Uc, xb, vs + 2 * D, bs + 2 * D,
                                            lenb, csave, nullptr, out);
  hpost_kernel<true><<<4096, 256, 0, stream>>>(Uc, xb, (const float4*)Ua,
                                               vs + 2 * D, bs + 2 * D, lenb, nullptr, out);
}